// Round 1
// 1107.113 us; speedup vs baseline: 1.0559x; 1.0559x over previous
//
#include <hip/hip_runtime.h>
#include <hip/hip_bf16.h>

// Windowed 3D attention transformer block, MI355X bf16-MFMA implementation.
// Residual stream fp32; GEMM/attention compute bf16 in, fp32 accumulate.
// R3: GEMM rewritten to 256x256 tile, BK=64, 8-wave phase-split schedule
//     (T1 XCD swizzle + T2 chunk-XOR LDS swizzle + T3/T4 counted-cover vmcnt
//      + T5 setprio). One vmcnt wait per 64 MFMA (was per 16), with loads
//     issued 2.5-4 phases ahead of their wait.

typedef __attribute__((ext_vector_type(4))) short short4v;
typedef __attribute__((ext_vector_type(8))) short short8v;
typedef __attribute__((ext_vector_type(4))) float f32x4;

__device__ __forceinline__ unsigned short f2bf(float f) {
  unsigned u = __float_as_uint(f);
  u += 0x7fffu + ((u >> 16) & 1u);   // RNE; inputs finite
  return (unsigned short)(u >> 16);
}

// async 16B global->LDS DMA; LDS dest = wave-uniform base + lane*16
__device__ __forceinline__ void gload_lds16(const unsigned short* g, unsigned short* l) {
  __builtin_amdgcn_global_load_lds(
      (const __attribute__((address_space(1))) unsigned int*)g,
      (__attribute__((address_space(3))) unsigned int*)l, 16, 0, 0);
}

// ---------------- weight prep (all 4 weights, one launch) ------------------
// wt element layout: [qkv 512x1536 ->786432][proj ->262144][w1 ->1048576][w2 ->1048576]
__global__ __launch_bounds__(256)
void wprep_all(const float* __restrict__ qkv_w, const float* __restrict__ proj_w,
               const float* __restrict__ w1, const float* __restrict__ w2,
               unsigned short* __restrict__ wt) {
  int idx = blockIdx.x * 256 + threadIdx.x;
  const float* w; int kbits, N, base;
  if (idx < 786432)       { w = qkv_w;  kbits = 9;  N = 1536; base = 0; }
  else if (idx < 1048576) { w = proj_w; kbits = 9;  N = 512;  base = 786432; }
  else if (idx < 2097152) { w = w1;     kbits = 9;  N = 2048; base = 1048576; }
  else                    { w = w2;     kbits = 11; N = 512;  base = 2097152; }
  int li = idx - base;
  int K = 1 << kbits;
  int n = li >> kbits, kk = li & (K - 1);
  wt[idx] = f2bf(w[(long)kk * N + n]);
}

// ---------------- LayerNorm (one wave per 512-elem row) --------------------
__global__ __launch_bounds__(256)
void ln_kernel(const float* __restrict__ src, const float* __restrict__ g,
               const float* __restrict__ bb, unsigned short* __restrict__ dst,
               const int gather) {
  const int lane = threadIdx.x & 63;
  const int row = blockIdx.x * 4 + (threadIdx.x >> 6);
  long srow;
  if (gather) {
    int n = row & 63, win = row >> 6;
    int w0 = win & 7, h0 = (win >> 3) & 7, d0 = (win >> 6) & 7, b2 = win >> 9;
    int dx = n & 3, dy = (n >> 2) & 3, dz = n >> 4;
    int od = (d0 * 4 + dz + 2) & 31, oh = (h0 * 4 + dy + 2) & 31, ow = (w0 * 4 + dx + 2) & 31;
    srow = (((long)b2 * 32 + od) * 32 + oh) * 32 + ow;
  } else {
    srow = row;
  }
  const float4* sp = (const float4*)(src + srow * 512);
  float4 x0 = sp[lane], x1 = sp[lane + 64];
  float sum = x0.x + x0.y + x0.z + x0.w + x1.x + x1.y + x1.z + x1.w;
  float sq  = x0.x*x0.x + x0.y*x0.y + x0.z*x0.z + x0.w*x0.w
            + x1.x*x1.x + x1.y*x1.y + x1.z*x1.z + x1.w*x1.w;
#pragma unroll
  for (int off = 1; off < 64; off <<= 1) {
    sum += __shfl_xor(sum, off, 64);
    sq  += __shfl_xor(sq, off, 64);
  }
  float mean = sum * (1.0f / 512.0f);
  float var  = sq * (1.0f / 512.0f) - mean * mean;
  float rstd = rsqrtf(var + 1e-5f);
  float4 g0 = ((const float4*)g)[lane], g1 = ((const float4*)g)[lane + 64];
  float4 b0 = ((const float4*)bb)[lane], b1v = ((const float4*)bb)[lane + 64];
  ushort4 o0, o1;
  o0.x = f2bf((x0.x - mean) * rstd * g0.x + b0.x);
  o0.y = f2bf((x0.y - mean) * rstd * g0.y + b0.y);
  o0.z = f2bf((x0.z - mean) * rstd * g0.z + b0.z);
  o0.w = f2bf((x0.w - mean) * rstd * g0.w + b0.w);
  o1.x = f2bf((x1.x - mean) * rstd * g1.x + b1v.x);
  o1.y = f2bf((x1.y - mean) * rstd * g1.y + b1v.y);
  o1.z = f2bf((x1.z - mean) * rstd * g1.z + b1v.z);
  o1.w = f2bf((x1.w - mean) * rstd * g1.w + b1v.w);
  *(ushort4*)(dst + (long)row * 512 + lane * 4) = o0;
  *(ushort4*)(dst + (long)row * 512 + 256 + lane * 4) = o1;
}

// ---------------- GEMM: C[M,N] = A[M,K](bf16) * Bt[N,K]^T + bias ----------
// 256x256 block tile, BK=64 double-buffered, 8 waves (2M x 4N), per-wave
// 128x64 output (8x4 16x16x32 MFMA fragments).
// LDS rows are 8 chunks of 16B; chunk slot c of row r holds global chunk
// c ^ (r&7)  (linear LDS dest for global_load_lds, pre-swizzled source).
// Schedule per K-tile: 4 phases x {ds_read | stage-issue ; barrier ;
// setprio(1) 16xMFMA setprio(0) ; barrier}; loads for tile t+1 issued in
// phases 0-1 of tile t; single vmcnt wait at the tile boundary.
template <int EPI>
__global__ __launch_bounds__(512, 2)
void gemm_bt(const unsigned short* __restrict__ A,
             const unsigned short* __restrict__ Bt,
             const float* __restrict__ bias, int K,
             void* __restrict__ out0,
             unsigned short* __restrict__ out1,
             unsigned short* __restrict__ out2,
             const float* __restrict__ res) {
  __shared__ unsigned short As[2][256 * 64];
  __shared__ unsigned short Bs[2][256 * 64];
  const int tid = threadIdx.x;
  const int lane = tid & 63;
  const int wv = tid >> 6;           // 0..7
  const int wm = wv >> 2;            // 0..1  (M half)
  const int wn = wv & 3;             // 0..3  (N quarter)
  const int quad = lane >> 4;
  const int l15 = lane & 15;

  // T1: bijective XCD swizzle (all grids are multiples of 8 blocks)
  const int gx = gridDim.x;
  const int nwg = gx * gridDim.y;
  const int bid = blockIdx.y * gx + blockIdx.x;
  const int cpx = nwg >> 3;
  const int wg2 = (bid & 7) * cpx + (bid >> 3);
  const int bx = wg2 % gx;
  const int by = wg2 / gx;
  const long row0 = (long)by * 256;
  const long col0 = (long)bx * 256;

  f32x4 acc[8][4] = {};

  // staging geometry: round j, wave wv, lane l covers LDS chunk
  // (j*8+wv)*64 + l  ->  row r = j*64 + wv*8 + (l>>3), chunk slot l&7,
  // which must hold global chunk (l&7) ^ (r&7) = (l&7) ^ (l>>3).
  const int srow = wv * 8 + (lane >> 3);
  const int scg  = (lane & 7) ^ (lane >> 3);
  const unsigned short* gA = A  + (row0 + srow) * K + scg * 8;
  const unsigned short* gB = Bt + (col0 + srow) * K + scg * 8;
  const long jmp = 64L * K;          // elements per 64-row staging round
  const int ldst = wv * 512;         // ushort offset; + j*4096 per round

#define STAGE_A(buf, koff) do {                                         \
    _Pragma("unroll")                                                   \
    for (int j = 0; j < 4; ++j)                                         \
      gload_lds16(gA + (koff) + j * jmp, &As[buf][ldst + j * 4096]);    \
  } while (0)
#define STAGE_B(buf, koff) do {                                         \
    _Pragma("unroll")                                                   \
    for (int j = 0; j < 4; ++j)                                         \
      gload_lds16(gB + (koff) + j * jmp, &Bs[buf][ldst + j * 4096]);    \
  } while (0)

  // fragment read bases: row = (wm*128|wn*64) + frag*16 + l15, global chunk
  // quad + 4*ks, LDS chunk = (quad+4*ks) ^ (row&7); row&7 == l15&7 here.
  const int co0 = ((quad)     ^ (l15 & 7)) * 8;
  const int co1 = ((quad + 4) ^ (l15 & 7)) * 8;
  const int aB0 = (wm * 128 + l15) * 64 + co0;
  const int aB1 = (wm * 128 + l15) * 64 + co1;
  const int bB0 = (wn * 64 + l15) * 64 + co0;
  const int bB1 = (wn * 64 + l15) * 64 + co1;

#define MFMA_ROW(mh)                                                    \
    _Pragma("unroll")                                                   \
    for (int i = 0; i < 4; ++i)                                         \
      _Pragma("unroll")                                                 \
      for (int nt = 0; nt < 4; ++nt)                                    \
        acc[(mh) * 4 + i][nt] = __builtin_amdgcn_mfma_f32_16x16x32_bf16( \
            af[i], bfrag[nt], acc[(mh) * 4 + i][nt], 0, 0, 0)

  const int nk = K >> 6;
  STAGE_A(0, 0);
  STAGE_B(0, 0);
  asm volatile("s_waitcnt vmcnt(0)" ::: "memory");
  __builtin_amdgcn_s_barrier();

  for (int t = 0; t < nk; ++t) {
    const int cur = t & 1, nxt = cur ^ 1;
    const int more = (t + 1 < nk);
    const int kn = (t + 1) << 6;
    const unsigned short* Ac = As[cur];
    const unsigned short* Bc = Bs[cur];
    short8v bfrag[4];
    // ---- phase 0: ks=0, mh=0; issue A(t+1)
    {
      short8v af[4];
#pragma unroll
      for (int nt = 0; nt < 4; ++nt) bfrag[nt] = *(const short8v*)&Bc[bB0 + nt * 1024];
#pragma unroll
      for (int i = 0; i < 4; ++i) af[i] = *(const short8v*)&Ac[aB0 + i * 1024];
      if (more) STAGE_A(nxt, kn);
      __builtin_amdgcn_s_barrier();
      __builtin_amdgcn_s_setprio(1);
      MFMA_ROW(0);
      __builtin_amdgcn_s_setprio(0);
      __builtin_amdgcn_s_barrier();
    }
    // ---- phase 1: ks=0, mh=1; issue B(t+1)
    {
      short8v af[4];
#pragma unroll
      for (int i = 0; i < 4; ++i) af[i] = *(const short8v*)&Ac[aB0 + (4 + i) * 1024];
      if (more) STAGE_B(nxt, kn);
      __builtin_amdgcn_s_barrier();
      __builtin_amdgcn_s_setprio(1);
      MFMA_ROW(1);
      __builtin_amdgcn_s_setprio(0);
      __builtin_amdgcn_s_barrier();
    }
    // ---- phase 2: ks=1, mh=0
    {
      short8v af[4];
#pragma unroll
      for (int nt = 0; nt < 4; ++nt) bfrag[nt] = *(const short8v*)&Bc[bB1 + nt * 1024];
#pragma unroll
      for (int i = 0; i < 4; ++i) af[i] = *(const short8v*)&Ac[aB1 + i * 1024];
      __builtin_amdgcn_s_barrier();
      __builtin_amdgcn_s_setprio(1);
      MFMA_ROW(0);
      __builtin_amdgcn_s_setprio(0);
      __builtin_amdgcn_s_barrier();
    }
    // ---- phase 3: ks=1, mh=1; tile-boundary sync (loads t+1 now covered
    //      by ~2.5-4 phases of MFMA; this is the only vmem wait per tile)
    {
      short8v af[4];
#pragma unroll
      for (int i = 0; i < 4; ++i) af[i] = *(const short8v*)&Ac[aB1 + (4 + i) * 1024];
      __builtin_amdgcn_s_barrier();
      __builtin_amdgcn_s_setprio(1);
      MFMA_ROW(1);
      __builtin_amdgcn_s_setprio(0);
      asm volatile("s_waitcnt vmcnt(0)" ::: "memory");
      __builtin_amdgcn_s_barrier();
    }
  }
#undef STAGE_A
#undef STAGE_B
#undef MFMA_ROW

#pragma unroll
  for (int mt = 0; mt < 8; ++mt) {
#pragma unroll
    for (int nt = 0; nt < 4; ++nt) {
#pragma unroll
      for (int r = 0; r < 4; ++r) {
        const long gr = row0 + wm * 128 + mt * 16 + quad * 4 + r;
        const long gc = col0 + wn * 64 + nt * 16 + l15;
        float val = acc[mt][nt][r] + bias[gc];
        if (EPI == 0) {
          int which = (int)(gc >> 9), rem = (int)gc & 511;
          int head = rem >> 6, hd = rem & 63;
          long win = gr >> 6, n = gr & 63;
          long base = (win * 8 + head) * 4096;
          unsigned short bv = f2bf(val);
          if (which == 0)      ((unsigned short*)out0)[base + n * 64 + hd] = bv;
          else if (which == 1) out1[base + n * 64 + hd] = bv;
          else                 out2[base + hd * 64 + n] = bv;   // v transposed
        } else if (EPI == 1) {
          int win = (int)(gr >> 6), n = (int)gr & 63;
          int w0 = win & 7, h0 = (win >> 3) & 7, d0 = (win >> 6) & 7, b2 = win >> 9;
          int dx = n & 3, dy = (n >> 2) & 3, dz = n >> 4;
          int od = (d0 * 4 + dz + 2) & 31, oh = (h0 * 4 + dy + 2) & 31, ow = (w0 * 4 + dx + 2) & 31;
          long addr = ((((long)b2 * 32 + od) * 32 + oh) * 32 + ow) * 512 + gc;
          ((float*)out0)[addr] = res[addr] + val;
        } else if (EPI == 2) {
          float ge = 0.5f * val * (1.0f + erff(val * 0.70710678118654752f));
          ((unsigned short*)out0)[gr * 2048 + gc] = f2bf(ge);
        } else {
          long addr = gr * 512 + gc;
          ((float*)out0)[addr] = res[addr] + val;
        }
      }
    }
  }
}

// ---------------- attention: one wave per (window, head) -------------------
__global__ __launch_bounds__(256)
void attn_kernel(const unsigned short* __restrict__ q,
                 const unsigned short* __restrict__ k,
                 const unsigned short* __restrict__ vt,
                 unsigned short* __restrict__ out) {
  __shared__ unsigned short Ps[4][64 * 72];
  const int lane = threadIdx.x & 63;
  const int wave = threadIdx.x >> 6;
  const int quad = lane >> 4;
  const int l15 = lane & 15;
  const int unit = blockIdx.x * 4 + wave;
  const int win = unit >> 3;
  const int head = unit & 7;
  const long base = (long)unit * 4096;

  f32x4 s[4][4] = {};
#pragma unroll
  for (int kk = 0; kk < 64; kk += 32) {
    short8v a[4], b[4];
#pragma unroll
    for (int t = 0; t < 4; ++t) {
      a[t] = *(const short8v*)(q + base + (t * 16 + l15) * 64 + kk + quad * 8);
      b[t] = *(const short8v*)(k + base + (t * 16 + l15) * 64 + kk + quad * 8);
    }
#pragma unroll
    for (int mt = 0; mt < 4; ++mt)
#pragma unroll
      for (int nt = 0; nt < 4; ++nt)
        s[mt][nt] = __builtin_amdgcn_mfma_f32_16x16x32_bf16(a[mt], b[nt], s[mt][nt], 0, 0, 0);
  }

  float lrow[4][4];
#pragma unroll
  for (int mt = 0; mt < 4; ++mt) {
#pragma unroll
    for (int r = 0; r < 4; ++r) {
      float v0 = s[mt][0][r] * 0.125f, v1 = s[mt][1][r] * 0.125f;
      float v2 = s[mt][2][r] * 0.125f, v3 = s[mt][3][r] * 0.125f;
      float mx = fmaxf(fmaxf(v0, v1), fmaxf(v2, v3));
#pragma unroll
      for (int off = 1; off < 16; off <<= 1) mx = fmaxf(mx, __shfl_xor(mx, off, 64));
      v0 = __expf(v0 - mx); v1 = __expf(v1 - mx);
      v2 = __expf(v2 - mx); v3 = __expf(v3 - mx);
      float sm = v0 + v1 + v2 + v3;
#pragma unroll
      for (int off = 1; off < 16; off <<= 1) sm += __shfl_xor(sm, off, 64);
      lrow[mt][r] = sm;
      int row = mt * 16 + quad * 4 + r;
      Ps[wave][row * 72 + 0 + l15]  = f2bf(v0);
      Ps[wave][row * 72 + 16 + l15] = f2bf(v1);
      Ps[wave][row * 72 + 32 + l15] = f2bf(v2);
      Ps[wave][row * 72 + 48 + l15] = f2bf(v3);
    }
  }
  __syncthreads();

  f32x4 o[4][4] = {};
#pragma unroll
  for (int kk = 0; kk < 64; kk += 32) {
    short8v a[4], b[4];
#pragma unroll
    for (int t = 0; t < 4; ++t) {
      a[t] = *(const short8v*)(&Ps[wave][(t * 16 + l15) * 72 + kk + quad * 8]);
      b[t] = *(const short8v*)(vt + base + (t * 16 + l15) * 64 + kk + quad * 8);
    }
#pragma unroll
    for (int mt = 0; mt < 4; ++mt)
#pragma unroll
      for (int nt = 0; nt < 4; ++nt)
        o[mt][nt] = __builtin_amdgcn_mfma_f32_16x16x32_bf16(a[mt], b[nt], o[mt][nt], 0, 0, 0);
  }

#pragma unroll
  for (int mt = 0; mt < 4; ++mt)
#pragma unroll
    for (int nt = 0; nt < 4; ++nt)
#pragma unroll
      for (int r = 0; r < 4; ++r) {
        int row = mt * 16 + quad * 4 + r;
        int col = nt * 16 + l15;
        float val = o[mt][nt][r] / lrow[mt][r];
        out[((long)win * 64 + row) * 512 + head * 64 + col] = f2bf(val);
      }
}

// ---------------- launch ---------------------------------------------------
extern "C" void kernel_launch(void* const* d_in, const int* in_sizes, int n_in,
                              void* d_out, int out_size, void* d_ws, size_t ws_size,
                              hipStream_t stream) {
  const float* x      = (const float*)d_in[0];
  const float* ln1_g  = (const float*)d_in[1];
  const float* ln1_b  = (const float*)d_in[2];
  const float* qkv_w  = (const float*)d_in[3];
  const float* qkv_b  = (const float*)d_in[4];
  const float* proj_w = (const float*)d_in[5];
  const float* proj_b = (const float*)d_in[6];
  const float* ln2_g  = (const float*)d_in[7];
  const float* ln2_b  = (const float*)d_in[8];
  const float* w1     = (const float*)d_in[9];
  const float* b1     = (const float*)d_in[10];
  const float* w2     = (const float*)d_in[11];
  const float* b2     = (const float*)d_in[12];

  // workspace layout (bytes); hid overlays attn_out+q+k+v (dead after proj)
  char* ws = (char*)d_ws;
  unsigned short* wt_all  = (unsigned short*)ws;
  unsigned short* wt_qkv  = (unsigned short*)(ws + 0);          // 1536x512 bf16
  unsigned short* wt_proj = (unsigned short*)(ws + 1572864);    // 512x512
  unsigned short* wt_1    = (unsigned short*)(ws + 2097152);    // 2048x512
  unsigned short* wt_2    = (unsigned short*)(ws + 4194304);    // 512x2048
  float*          xo      = (float*)(ws + 8388608);             // 128 MiB fp32
  unsigned short* h       = (unsigned short*)(ws + 142606336);  // 64 MiB bf16 (h, then h2)
  unsigned short* attno   = (unsigned short*)(ws + 209715200);  // 64 MiB
  unsigned short* qb      = (unsigned short*)(ws + 276824064);  // 64 MiB
  unsigned short* kb      = (unsigned short*)(ws + 343932928);  // 64 MiB
  unsigned short* vb      = (unsigned short*)(ws + 411041792);  // 64 MiB
  unsigned short* hid     = (unsigned short*)(ws + 209715200);  // 256 MiB overlay
  float* out = (float*)d_out;

  wprep_all<<<12288, 256, 0, stream>>>(qkv_w, proj_w, w1, w2, wt_all);

  ln_kernel<<<16384, 256, 0, stream>>>(x, ln1_g, ln1_b, h, 1);
  gemm_bt<0><<<dim3(6, 256), 512, 0, stream>>>(h, wt_qkv, qkv_b, 512, qb, kb, vb, nullptr);
  attn_kernel<<<2048, 256, 0, stream>>>(qb, kb, vb, attno);
  gemm_bt<1><<<dim3(2, 256), 512, 0, stream>>>(attno, wt_proj, proj_b, 512, xo, nullptr, nullptr, x);
  ln_kernel<<<16384, 256, 0, stream>>>(xo, ln2_g, ln2_b, h, 0);
  gemm_bt<2><<<dim3(8, 256), 512, 0, stream>>>(h, wt_1, b1, 512, hid, nullptr, nullptr, nullptr);
  gemm_bt<3><<<dim3(2, 256), 512, 0, stream>>>(hid, wt_2, b2, 2048, out, nullptr, nullptr, xo);
}

// Round 3
// 1092.855 us; speedup vs baseline: 1.0697x; 1.0130x over previous
//
#include <hip/hip_runtime.h>
#include <hip/hip_bf16.h>

// Windowed 3D attention transformer block, MI355X bf16-MFMA implementation.
// Residual stream fp32; GEMM/attention compute bf16 in, fp32 accumulate.
// R4 (resubmitted R5 — prior bench was an infra failure, no kernel signal):
//     GEMM main loop de-lockstepped -> one barrier per K-tile (guide's
//     verified minimum 2-phase template): STAGE(nxt) issued first, then
//     compiler-scheduled ds_read/MFMA interleave, __syncthreads at tile end.
//     Removes the 8-barrier/tile serialization that pinned MfmaUtil at 21%.
//     EPI=2 epilogue: libm erff -> branch-free A&S 7.1.26 erf (1.5e-7).

typedef __attribute__((ext_vector_type(4))) short short4v;
typedef __attribute__((ext_vector_type(8))) short short8v;
typedef __attribute__((ext_vector_type(4))) float f32x4;

__device__ __forceinline__ unsigned short f2bf(float f) {
  unsigned u = __float_as_uint(f);
  u += 0x7fffu + ((u >> 16) & 1u);   // RNE; inputs finite
  return (unsigned short)(u >> 16);
}

// branch-free erf, Abramowitz-Stegun 7.1.26, |err| <= 1.5e-7
__device__ __forceinline__ float erf_fast(float x) {
  float ax = fabsf(x);
  float y = 1.0f + 0.3275911f * ax;
  float t;
  asm("v_rcp_f32 %0, %1" : "=v"(t) : "v"(y));           // ~1ulp, fine at 1e-7 scale
  float p = t * (0.254829592f +
            t * (-0.284496736f +
            t * (1.421413741f +
            t * (-1.453152027f +
            t * 1.061405429f))));
  float e = __expf(-ax * ax);
  float r = 1.0f - p * e;
  return copysignf(r, x);
}

// async 16B global->LDS DMA; LDS dest = wave-uniform base + lane*16
__device__ __forceinline__ void gload_lds16(const unsigned short* g, unsigned short* l) {
  __builtin_amdgcn_global_load_lds(
      (const __attribute__((address_space(1))) unsigned int*)g,
      (__attribute__((address_space(3))) unsigned int*)l, 16, 0, 0);
}

// ---------------- weight prep (all 4 weights, one launch) ------------------
// wt element layout: [qkv 512x1536 ->786432][proj ->262144][w1 ->1048576][w2 ->1048576]
__global__ __launch_bounds__(256)
void wprep_all(const float* __restrict__ qkv_w, const float* __restrict__ proj_w,
               const float* __restrict__ w1, const float* __restrict__ w2,
               unsigned short* __restrict__ wt) {
  int idx = blockIdx.x * 256 + threadIdx.x;
  const float* w; int kbits, N, base;
  if (idx < 786432)       { w = qkv_w;  kbits = 9;  N = 1536; base = 0; }
  else if (idx < 1048576) { w = proj_w; kbits = 9;  N = 512;  base = 786432; }
  else if (idx < 2097152) { w = w1;     kbits = 9;  N = 2048; base = 1048576; }
  else                    { w = w2;     kbits = 11; N = 512;  base = 2097152; }
  int li = idx - base;
  int K = 1 << kbits;
  int n = li >> kbits, kk = li & (K - 1);
  wt[idx] = f2bf(w[(long)kk * N + n]);
}

// ---------------- LayerNorm (one wave per 512-elem row) --------------------
__global__ __launch_bounds__(256)
void ln_kernel(const float* __restrict__ src, const float* __restrict__ g,
               const float* __restrict__ bb, unsigned short* __restrict__ dst,
               const int gather) {
  const int lane = threadIdx.x & 63;
  const int row = blockIdx.x * 4 + (threadIdx.x >> 6);
  long srow;
  if (gather) {
    int n = row & 63, win = row >> 6;
    int w0 = win & 7, h0 = (win >> 3) & 7, d0 = (win >> 6) & 7, b2 = win >> 9;
    int dx = n & 3, dy = (n >> 2) & 3, dz = n >> 4;
    int od = (d0 * 4 + dz + 2) & 31, oh = (h0 * 4 + dy + 2) & 31, ow = (w0 * 4 + dx + 2) & 31;
    srow = (((long)b2 * 32 + od) * 32 + oh) * 32 + ow;
  } else {
    srow = row;
  }
  const float4* sp = (const float4*)(src + srow * 512);
  float4 x0 = sp[lane], x1 = sp[lane + 64];
  float sum = x0.x + x0.y + x0.z + x0.w + x1.x + x1.y + x1.z + x1.w;
  float sq  = x0.x*x0.x + x0.y*x0.y + x0.z*x0.z + x0.w*x0.w
            + x1.x*x1.x + x1.y*x1.y + x1.z*x1.z + x1.w*x1.w;
#pragma unroll
  for (int off = 1; off < 64; off <<= 1) {
    sum += __shfl_xor(sum, off, 64);
    sq  += __shfl_xor(sq, off, 64);
  }
  float mean = sum * (1.0f / 512.0f);
  float var  = sq * (1.0f / 512.0f) - mean * mean;
  float rstd = rsqrtf(var + 1e-5f);
  float4 g0 = ((const float4*)g)[lane], g1 = ((const float4*)g)[lane + 64];
  float4 b0 = ((const float4*)bb)[lane], b1v = ((const float4*)bb)[lane + 64];
  ushort4 o0, o1;
  o0.x = f2bf((x0.x - mean) * rstd * g0.x + b0.x);
  o0.y = f2bf((x0.y - mean) * rstd * g0.y + b0.y);
  o0.z = f2bf((x0.z - mean) * rstd * g0.z + b0.z);
  o0.w = f2bf((x0.w - mean) * rstd * g0.w + b0.w);
  o1.x = f2bf((x1.x - mean) * rstd * g1.x + b1v.x);
  o1.y = f2bf((x1.y - mean) * rstd * g1.y + b1v.y);
  o1.z = f2bf((x1.z - mean) * rstd * g1.z + b1v.z);
  o1.w = f2bf((x1.w - mean) * rstd * g1.w + b1v.w);
  *(ushort4*)(dst + (long)row * 512 + lane * 4) = o0;
  *(ushort4*)(dst + (long)row * 512 + 256 + lane * 4) = o1;
}

// ---------------- GEMM: C[M,N] = A[M,K](bf16) * Bt[N,K]^T + bias ----------
// 256x256 block tile, BK=64 double-buffered, 8 waves (2M x 4N), per-wave
// 128x64 output (8x4 16x16x32 MFMA fragments).
// LDS rows are 8 chunks of 16B; chunk slot c of row r holds global chunk
// c ^ (r&7)  (linear LDS dest for global_load_lds, pre-swizzled source).
// Main loop (minimum 2-phase template): issue STAGE(nxt) first, then
// ds_read/MFMA for cur (compiler interleaves with fine lgkmcnt), then one
// __syncthreads (drains vmcnt for nxt + protects cur for re-staging).
template <int EPI>
__global__ __launch_bounds__(512, 2)
void gemm_bt(const unsigned short* __restrict__ A,
             const unsigned short* __restrict__ Bt,
             const float* __restrict__ bias, int K,
             void* __restrict__ out0,
             unsigned short* __restrict__ out1,
             unsigned short* __restrict__ out2,
             const float* __restrict__ res) {
  __shared__ unsigned short As[2][256 * 64];
  __shared__ unsigned short Bs[2][256 * 64];
  const int tid = threadIdx.x;
  const int lane = tid & 63;
  const int wv = tid >> 6;           // 0..7
  const int wm = wv >> 2;            // 0..1  (M half)
  const int wn = wv & 3;             // 0..3  (N quarter)
  const int quad = lane >> 4;
  const int l15 = lane & 15;

  // T1: bijective XCD swizzle (all grids are multiples of 8 blocks)
  const int gx = gridDim.x;
  const int nwg = gx * gridDim.y;
  const int bid = blockIdx.y * gx + blockIdx.x;
  const int cpx = nwg >> 3;
  const int wg2 = (bid & 7) * cpx + (bid >> 3);
  const int bx = wg2 % gx;
  const int by = wg2 / gx;
  const long row0 = (long)by * 256;
  const long col0 = (long)bx * 256;

  f32x4 acc[8][4] = {};

  // staging geometry: round j, wave wv, lane l covers LDS chunk
  // (j*8+wv)*64 + l  ->  row r = j*64 + wv*8 + (l>>3), chunk slot l&7,
  // which must hold global chunk (l&7) ^ (r&7) = (l&7) ^ (l>>3).
  const int srow = wv * 8 + (lane >> 3);
  const int scg  = (lane & 7) ^ (lane >> 3);
  const unsigned short* gA = A  + (row0 + srow) * K + scg * 8;
  const unsigned short* gB = Bt + (col0 + srow) * K + scg * 8;
  const long jmp = 64L * K;          // elements per 64-row staging round
  const int ldst = wv * 512;         // ushort offset; + j*4096 per round

#define STAGE_A(buf, koff) do {                                         \
    _Pragma("unroll")                                                   \
    for (int j = 0; j < 4; ++j)                                         \
      gload_lds16(gA + (koff) + j * jmp, &As[buf][ldst + j * 4096]);    \
  } while (0)
#define STAGE_B(buf, koff) do {                                         \
    _Pragma("unroll")                                                   \
    for (int j = 0; j < 4; ++j)                                         \
      gload_lds16(gB + (koff) + j * jmp, &Bs[buf][ldst + j * 4096]);    \
  } while (0)

  // fragment read bases: row = (wm*128|wn*64) + frag*16 + l15, global chunk
  // quad + 4*ks, LDS chunk = (quad+4*ks) ^ (row&7); row&7 == l15&7 here.
  const int co0 = ((quad)     ^ (l15 & 7)) * 8;
  const int co1 = ((quad + 4) ^ (l15 & 7)) * 8;
  const int aB0 = (wm * 128 + l15) * 64 + co0;
  const int aB1 = (wm * 128 + l15) * 64 + co1;
  const int bB0 = (wn * 64 + l15) * 64 + co0;
  const int bB1 = (wn * 64 + l15) * 64 + co1;

  const int nk = K >> 6;
  STAGE_A(0, 0);
  STAGE_B(0, 0);
  __syncthreads();                   // drains prologue DMA (vmcnt 0) + sync

  for (int t = 0; t < nk; ++t) {
    const int cur = t & 1, nxt = cur ^ 1;
    const unsigned short* Ac = As[cur];
    const unsigned short* Bc = Bs[cur];
    if (t + 1 < nk) {                // issue next tile's DMA before compute
      const int kn = (t + 1) << 6;
      STAGE_A(nxt, kn);
      STAGE_B(nxt, kn);
    }
    // B fragments for both k-subtiles (stay live across both M halves)
    short8v bf0[4], bf1[4];
#pragma unroll
    for (int nt = 0; nt < 4; ++nt) {
      bf0[nt] = *(const short8v*)&Bc[bB0 + nt * 1024];
      bf1[nt] = *(const short8v*)&Bc[bB1 + nt * 1024];
    }
#pragma unroll
    for (int mh = 0; mh < 2; ++mh) {
      short8v af0[4], af1[4];
#pragma unroll
      for (int i = 0; i < 4; ++i) {
        af0[i] = *(const short8v*)&Ac[aB0 + (mh * 4 + i) * 1024];
        af1[i] = *(const short8v*)&Ac[aB1 + (mh * 4 + i) * 1024];
      }
      __builtin_amdgcn_s_setprio(1);
#pragma unroll
      for (int i = 0; i < 4; ++i)
#pragma unroll
        for (int nt = 0; nt < 4; ++nt)
          acc[mh * 4 + i][nt] = __builtin_amdgcn_mfma_f32_16x16x32_bf16(
              af0[i], bf0[nt], acc[mh * 4 + i][nt], 0, 0, 0);
#pragma unroll
      for (int i = 0; i < 4; ++i)
#pragma unroll
        for (int nt = 0; nt < 4; ++nt)
          acc[mh * 4 + i][nt] = __builtin_amdgcn_mfma_f32_16x16x32_bf16(
              af1[i], bf1[nt], acc[mh * 4 + i][nt], 0, 0, 0);
      __builtin_amdgcn_s_setprio(0);
    }
    __syncthreads();                 // drains nxt DMA; cur free to re-stage
  }
#undef STAGE_A
#undef STAGE_B

#pragma unroll
  for (int mt = 0; mt < 8; ++mt) {
#pragma unroll
    for (int nt = 0; nt < 4; ++nt) {
#pragma unroll
      for (int r = 0; r < 4; ++r) {
        const long gr = row0 + wm * 128 + mt * 16 + quad * 4 + r;
        const long gc = col0 + wn * 64 + nt * 16 + l15;
        float val = acc[mt][nt][r] + bias[gc];
        if (EPI == 0) {
          int which = (int)(gc >> 9), rem = (int)gc & 511;
          int head = rem >> 6, hd = rem & 63;
          long win = gr >> 6, n = gr & 63;
          long base = (win * 8 + head) * 4096;
          unsigned short bv = f2bf(val);
          if (which == 0)      ((unsigned short*)out0)[base + n * 64 + hd] = bv;
          else if (which == 1) out1[base + n * 64 + hd] = bv;
          else                 out2[base + hd * 64 + n] = bv;   // v transposed
        } else if (EPI == 1) {
          int win = (int)(gr >> 6), n = (int)gr & 63;
          int w0 = win & 7, h0 = (win >> 3) & 7, d0 = (win >> 6) & 7, b2 = win >> 9;
          int dx = n & 3, dy = (n >> 2) & 3, dz = n >> 4;
          int od = (d0 * 4 + dz + 2) & 31, oh = (h0 * 4 + dy + 2) & 31, ow = (w0 * 4 + dx + 2) & 31;
          long addr = ((((long)b2 * 32 + od) * 32 + oh) * 32 + ow) * 512 + gc;
          ((float*)out0)[addr] = res[addr] + val;
        } else if (EPI == 2) {
          float ge = 0.5f * val * (1.0f + erf_fast(val * 0.70710678118654752f));
          ((unsigned short*)out0)[gr * 2048 + gc] = f2bf(ge);
        } else {
          long addr = gr * 512 + gc;
          ((float*)out0)[addr] = res[addr] + val;
        }
      }
    }
  }
}

// ---------------- attention: one wave per (window, head) -------------------
__global__ __launch_bounds__(256)
void attn_kernel(const unsigned short* __restrict__ q,
                 const unsigned short* __restrict__ k,
                 const unsigned short* __restrict__ vt,
                 unsigned short* __restrict__ out) {
  __shared__ unsigned short Ps[4][64 * 72];
  const int lane = threadIdx.x & 63;
  const int wave = threadIdx.x >> 6;
  const int quad = lane >> 4;
  const int l15 = lane & 15;
  const int unit = blockIdx.x * 4 + wave;
  const int win = unit >> 3;
  const int head = unit & 7;
  const long base = (long)unit * 4096;

  f32x4 s[4][4] = {};
#pragma unroll
  for (int kk = 0; kk < 64; kk += 32) {
    short8v a[4], b[4];
#pragma unroll
    for (int t = 0; t < 4; ++t) {
      a[t] = *(const short8v*)(q + base + (t * 16 + l15) * 64 + kk + quad * 8);
      b[t] = *(const short8v*)(k + base + (t * 16 + l15) * 64 + kk + quad * 8);
    }
#pragma unroll
    for (int mt = 0; mt < 4; ++mt)
#pragma unroll
      for (int nt = 0; nt < 4; ++nt)
        s[mt][nt] = __builtin_amdgcn_mfma_f32_16x16x32_bf16(a[mt], b[nt], s[mt][nt], 0, 0, 0);
  }

  float lrow[4][4];
#pragma unroll
  for (int mt = 0; mt < 4; ++mt) {
#pragma unroll
    for (int r = 0; r < 4; ++r) {
      float v0 = s[mt][0][r] * 0.125f, v1 = s[mt][1][r] * 0.125f;
      float v2 = s[mt][2][r] * 0.125f, v3 = s[mt][3][r] * 0.125f;
      float mx = fmaxf(fmaxf(v0, v1), fmaxf(v2, v3));
#pragma unroll
      for (int off = 1; off < 16; off <<= 1) mx = fmaxf(mx, __shfl_xor(mx, off, 64));
      v0 = __expf(v0 - mx); v1 = __expf(v1 - mx);
      v2 = __expf(v2 - mx); v3 = __expf(v3 - mx);
      float sm = v0 + v1 + v2 + v3;
#pragma unroll
      for (int off = 1; off < 16; off <<= 1) sm += __shfl_xor(sm, off, 64);
      lrow[mt][r] = sm;
      int row = mt * 16 + quad * 4 + r;
      Ps[wave][row * 72 + 0 + l15]  = f2bf(v0);
      Ps[wave][row * 72 + 16 + l15] = f2bf(v1);
      Ps[wave][row * 72 + 32 + l15] = f2bf(v2);
      Ps[wave][row * 72 + 48 + l15] = f2bf(v3);
    }
  }
  __syncthreads();

  f32x4 o[4][4] = {};
#pragma unroll
  for (int kk = 0; kk < 64; kk += 32) {
    short8v a[4], b[4];
#pragma unroll
    for (int t = 0; t < 4; ++t) {
      a[t] = *(const short8v*)(&Ps[wave][(t * 16 + l15) * 72 + kk + quad * 8]);
      b[t] = *(const short8v*)(vt + base + (t * 16 + l15) * 64 + kk + quad * 8);
    }
#pragma unroll
    for (int mt = 0; mt < 4; ++mt)
#pragma unroll
      for (int nt = 0; nt < 4; ++nt)
        o[mt][nt] = __builtin_amdgcn_mfma_f32_16x16x32_bf16(a[mt], b[nt], o[mt][nt], 0, 0, 0);
  }

#pragma unroll
  for (int mt = 0; mt < 4; ++mt)
#pragma unroll
    for (int nt = 0; nt < 4; ++nt)
#pragma unroll
      for (int r = 0; r < 4; ++r) {
        int row = mt * 16 + quad * 4 + r;
        int col = nt * 16 + l15;
        float val = o[mt][nt][r] / lrow[mt][r];
        out[((long)win * 64 + row) * 512 + head * 64 + col] = f2bf(val);
      }
}

// ---------------- launch ---------------------------------------------------
extern "C" void kernel_launch(void* const* d_in, const int* in_sizes, int n_in,
                              void* d_out, int out_size, void* d_ws, size_t ws_size,
                              hipStream_t stream) {
  const float* x      = (const float*)d_in[0];
  const float* ln1_g  = (const float*)d_in[1];
  const float* ln1_b  = (const float*)d_in[2];
  const float* qkv_w  = (const float*)d_in[3];
  const float* qkv_b  = (const float*)d_in[4];
  const float* proj_w = (const float*)d_in[5];
  const float* proj_b = (const float*)d_in[6];
  const float* ln2_g  = (const float*)d_in[7];
  const float* ln2_b  = (const float*)d_in[8];
  const float* w1     = (const float*)d_in[9];
  const float* b1     = (const float*)d_in[10];
  const float* w2     = (const float*)d_in[11];
  const float* b2     = (const float*)d_in[12];

  // workspace layout (bytes); hid overlays attn_out+q+k+v (dead after proj)
  char* ws = (char*)d_ws;
  unsigned short* wt_all  = (unsigned short*)ws;
  unsigned short* wt_qkv  = (unsigned short*)(ws + 0);          // 1536x512 bf16
  unsigned short* wt_proj = (unsigned short*)(ws + 1572864);    // 512x512
  unsigned short* wt_1    = (unsigned short*)(ws + 2097152);    // 2048x512
  unsigned short* wt_2    = (unsigned short*)(ws + 4194304);    // 512x2048
  float*          xo      = (float*)(ws + 8388608);             // 128 MiB fp32
  unsigned short* h       = (unsigned short*)(ws + 142606336);  // 64 MiB bf16 (h, then h2)
  unsigned short* attno   = (unsigned short*)(ws + 209715200);  // 64 MiB
  unsigned short* qb      = (unsigned short*)(ws + 276824064);  // 64 MiB
  unsigned short* kb      = (unsigned short*)(ws + 343932928);  // 64 MiB
  unsigned short* vb      = (unsigned short*)(ws + 411041792);  // 64 MiB
  unsigned short* hid     = (unsigned short*)(ws + 209715200);  // 256 MiB overlay
  float* out = (float*)d_out;

  wprep_all<<<12288, 256, 0, stream>>>(qkv_w, proj_w, w1, w2, wt_all);

  ln_kernel<<<16384, 256, 0, stream>>>(x, ln1_g, ln1_b, h, 1);
  gemm_bt<0><<<dim3(6, 256), 512, 0, stream>>>(h, wt_qkv, qkv_b, 512, qb, kb, vb, nullptr);
  attn_kernel<<<2048, 256, 0, stream>>>(qb, kb, vb, attno);
  gemm_bt<1><<<dim3(2, 256), 512, 0, stream>>>(attno, wt_proj, proj_b, 512, xo, nullptr, nullptr, x);
  ln_kernel<<<16384, 256, 0, stream>>>(xo, ln2_g, ln2_b, h, 0);
  gemm_bt<2><<<dim3(8, 256), 512, 0, stream>>>(h, wt_1, b1, 512, hid, nullptr, nullptr, nullptr);
  gemm_bt<3><<<dim3(2, 256), 512, 0, stream>>>(hid, wt_2, b2, 2048, out, nullptr, nullptr, xo);
}